// Round 1
// baseline (1165.448 us; speedup 1.0000x reference)
//
#include <hip/hip_runtime.h>
#include <math.h>

// Capsule dynamic routing, fused-recompute formulation.
// B=512, R=1152, C=10, O=16, I=8, fp32.
// Key identities:
//   iter0: c_ij = 1/10 uniform  -> s0 = 0.1 * sum_r u_hat
//   iter2: b2 = agr(u,v0)+agr(u,v1) = u . (v0+v1)  -> keep running vsum only
// u_hat is recomputed each pass (never materialized: 377MB avoided).

#define R_TOT 1152
#define C_N 10
#define O_N 16
#define I_N 8
#define B_TOT 512
#define RT 64        // r tiles
#define RCHUNK 18    // 1152 / 64
#define BTILES 8     // 512 / 64  (64 b per block)

// lane mapping inside a wave: ol = lane&3 owns o in [ol*4, ol*4+4); bl = lane>>2 (16 b / wave)
template<bool UNIFORM>
__global__ __launch_bounds__(256) void acc_kernel(
    const float* __restrict__ x, const float* __restrict__ W,
    const float* __restrict__ vsum, float* __restrict__ s)
{
  const int tid   = threadIdx.x;
  const int wave  = tid >> 6;
  const int lane  = tid & 63;
  const int ol    = lane & 3;
  const int bl    = lane >> 2;
  const int obase = ol * 4;
  const int btile = blockIdx.x / RT;
  const int rtile = blockIdx.x % RT;
  const int b     = btile * 64 + wave * 16 + bl;
  const int r0    = rtile * RCHUNK;

  float vf[C_N][4];
  if constexpr (!UNIFORM) {
    #pragma unroll
    for (int c = 0; c < C_N; ++c) {
      const float4 t = *reinterpret_cast<const float4*>(&vsum[(b * C_N + c) * O_N + obase]);
      vf[c][0] = t.x; vf[c][1] = t.y; vf[c][2] = t.z; vf[c][3] = t.w;
    }
  }

  float sacc[C_N][4];
  #pragma unroll
  for (int c = 0; c < C_N; ++c)
    #pragma unroll
    for (int j = 0; j < 4; ++j) sacc[c][j] = 0.0f;

  #pragma unroll 1
  for (int r = r0; r < r0 + RCHUNK; ++r) {
    const float4* xp = reinterpret_cast<const float4*>(&x[((size_t)b * R_TOT + r) * I_N]);
    const float4 xa = xp[0];
    const float4 xb = xp[1];
    const float* Wr = &W[(size_t)r * (C_N * O_N * I_N)];

    float u[C_N][4];
    #pragma unroll
    for (int c = 0; c < C_N; ++c) {
      const float4* wp = reinterpret_cast<const float4*>(&Wr[(c * O_N + obase) * I_N]);
      #pragma unroll
      for (int j = 0; j < 4; ++j) {
        const float4 w0 = wp[2 * j];
        const float4 w1 = wp[2 * j + 1];
        u[c][j] = w0.x * xa.x + w0.y * xa.y + w0.z * xa.z + w0.w * xa.w
                + w1.x * xb.x + w1.y * xb.y + w1.z * xb.z + w1.w * xb.w;
      }
    }

    if constexpr (UNIFORM) {
      #pragma unroll
      for (int c = 0; c < C_N; ++c)
        #pragma unroll
        for (int j = 0; j < 4; ++j) sacc[c][j] += u[c][j];
    } else {
      // agreement (cumulative): bij[c] = sum_o u[c][o] * vsum[b,c,o]
      float bij[C_N];
      #pragma unroll
      for (int c = 0; c < C_N; ++c) {
        float a = u[c][0] * vf[c][0] + u[c][1] * vf[c][1]
                + u[c][2] * vf[c][2] + u[c][3] * vf[c][3];
        a += __shfl_xor(a, 1);
        a += __shfl_xor(a, 2);
        bij[c] = a;
      }
      // softmax over c (10 values, in-register)
      float m = bij[0];
      #pragma unroll
      for (int c = 1; c < C_N; ++c) m = fmaxf(m, bij[c]);
      float e[C_N];
      float den = 0.0f;
      #pragma unroll
      for (int c = 0; c < C_N; ++c) { e[c] = __expf(bij[c] - m); den += e[c]; }
      const float inv = __builtin_amdgcn_rcpf(den);
      #pragma unroll
      for (int c = 0; c < C_N; ++c) {
        const float cc = e[c] * inv;
        #pragma unroll
        for (int j = 0; j < 4; ++j) sacc[c][j] += cc * u[c][j];
      }
    }
  }

  const float scale = UNIFORM ? 0.1f : 1.0f;
  #pragma unroll
  for (int c = 0; c < C_N; ++c)
    #pragma unroll
    for (int j = 0; j < 4; ++j)
      atomicAdd(&s[(b * C_N + c) * O_N + obase + j], sacc[c][j] * scale);
}

// squash over O=16 per (b,c) group; 16 consecutive lanes per group.
// MODE 0: vsum = v ; MODE 1: vsum += v ; MODE 2: out = v
template<int MODE>
__global__ __launch_bounds__(256) void squash_kernel(
    const float* __restrict__ s, float* __restrict__ vsum, float* __restrict__ out)
{
  const int gt = blockIdx.x * 256 + threadIdx.x;   // 0 .. 81919
  const int o  = gt & 15;
  const int g  = gt >> 4;                          // b*10 + c
  const float sv = s[g * O_N + o];
  float sq = sv * sv;
  sq += __shfl_xor(sq, 1);
  sq += __shfl_xor(sq, 2);
  sq += __shfl_xor(sq, 4);
  sq += __shfl_xor(sq, 8);
  const float scale = sq / (1.0f + sq) * rsqrtf(sq + 1e-8f);
  const float v = scale * sv;
  if constexpr (MODE == 0)      vsum[g * O_N + o] = v;
  else if constexpr (MODE == 1) vsum[g * O_N + o] += v;
  else                          out[g * O_N + o] = v;
}

extern "C" void kernel_launch(void* const* d_in, const int* in_sizes, int n_in,
                              void* d_out, int out_size, void* d_ws, size_t ws_size,
                              hipStream_t stream) {
  (void)in_sizes; (void)n_in; (void)out_size; (void)ws_size;
  const float* x = (const float*)d_in[0];
  const float* W = (const float*)d_in[1];
  float* out  = (float*)d_out;        // doubles as vsum scratch; fully rewritten with v2 at the end
  float* s    = (float*)d_ws;         // 512*10*16 floats = 327,680 B

  const size_t SB = (size_t)B_TOT * C_N * O_N * sizeof(float);
  const dim3 accGrid(BTILES * RT), blk(256), sqGrid(320);

  // iter 0: uniform coefficients
  hipMemsetAsync(s, 0, SB, stream);
  hipLaunchKernelGGL((acc_kernel<true>), accGrid, blk, 0, stream, x, W, nullptr, s);
  hipLaunchKernelGGL((squash_kernel<0>), sqGrid, blk, 0, stream, s, out, out);   // vsum = v0

  // iter 1
  hipMemsetAsync(s, 0, SB, stream);
  hipLaunchKernelGGL((acc_kernel<false>), accGrid, blk, 0, stream, x, W, out, s);
  hipLaunchKernelGGL((squash_kernel<1>), sqGrid, blk, 0, stream, s, out, out);   // vsum = v0+v1

  // iter 2
  hipMemsetAsync(s, 0, SB, stream);
  hipLaunchKernelGGL((acc_kernel<false>), accGrid, blk, 0, stream, x, W, out, s);
  hipLaunchKernelGGL((squash_kernel<2>), sqGrid, blk, 0, stream, s, out, out);   // out = v2
}

// Round 2
// 976.803 us; speedup vs baseline: 1.1931x; 1.1931x over previous
//
#include <hip/hip_runtime.h>
#include <math.h>

// Capsule dynamic routing, fused-recompute formulation.
// B=512, R=1152, C=10, O=16, I=8, fp32.
// Identities:
//   iter0: c_ij = 1/10 uniform  -> s0 = 0.1 * sum_r u_hat
//   iter2: b2 = agr(u,v0)+agr(u,v1) = u . (v0+v1)  -> keep running vsum only
// u_hat recomputed each pass (377MB never materialized).
// R1 change: global atomicAdd reduction (80MB of serialized memory-side
// atomic traffic, 97% stall) -> per-rtile partials in d_ws + fused
// reduce+squash kernel. No memsets needed (partials fully overwritten).

#define R_TOT 1152
#define C_N 10
#define O_N 16
#define I_N 8
#define B_TOT 512
#define SEG (B_TOT * C_N * O_N)   // 81920 floats per partial slice

// lane mapping in a wave: ol = lane&3 owns o in [ol*4, ol*4+4); bl = lane>>2 (16 b / wave)
// grid: (RT, 8)  -> blockIdx.x = rtile, blockIdx.y = btile (64 b per block)
template<bool UNIFORM>
__global__ __launch_bounds__(256) void acc_kernel(
    const float* __restrict__ x, const float* __restrict__ W,
    const float* __restrict__ vsum, float* __restrict__ part, int RCH)
{
  const int tid   = threadIdx.x;
  const int wave  = tid >> 6;
  const int lane  = tid & 63;
  const int ol    = lane & 3;
  const int bl    = lane >> 2;
  const int obase = ol * 4;
  const int rtile = blockIdx.x;
  const int btile = blockIdx.y;
  const int b     = btile * 64 + wave * 16 + bl;
  const int r0    = rtile * RCH;

  float vf[C_N][4];
  if constexpr (!UNIFORM) {
    #pragma unroll
    for (int c = 0; c < C_N; ++c) {
      const float4 t = *reinterpret_cast<const float4*>(&vsum[(b * C_N + c) * O_N + obase]);
      vf[c][0] = t.x; vf[c][1] = t.y; vf[c][2] = t.z; vf[c][3] = t.w;
    }
  }

  float sacc[C_N][4];
  #pragma unroll
  for (int c = 0; c < C_N; ++c)
    #pragma unroll
    for (int j = 0; j < 4; ++j) sacc[c][j] = 0.0f;

  #pragma unroll 1
  for (int r = r0; r < r0 + RCH; ++r) {
    const float4* xp = reinterpret_cast<const float4*>(&x[((size_t)b * R_TOT + r) * I_N]);
    const float4 xa = xp[0];
    const float4 xb = xp[1];
    const float* Wr = &W[(size_t)r * (C_N * O_N * I_N)];

    float u[C_N][4];
    #pragma unroll
    for (int c = 0; c < C_N; ++c) {
      const float4* wp = reinterpret_cast<const float4*>(&Wr[(c * O_N + obase) * I_N]);
      #pragma unroll
      for (int j = 0; j < 4; ++j) {
        const float4 w0 = wp[2 * j];
        const float4 w1 = wp[2 * j + 1];
        u[c][j] = w0.x * xa.x + w0.y * xa.y + w0.z * xa.z + w0.w * xa.w
                + w1.x * xb.x + w1.y * xb.y + w1.z * xb.z + w1.w * xb.w;
      }
    }

    if constexpr (UNIFORM) {
      #pragma unroll
      for (int c = 0; c < C_N; ++c)
        #pragma unroll
        for (int j = 0; j < 4; ++j) sacc[c][j] += u[c][j];
    } else {
      // agreement (cumulative): bij[c] = sum_o u[c][o] * vsum[b,c,o]
      float bij[C_N];
      #pragma unroll
      for (int c = 0; c < C_N; ++c) {
        float a = u[c][0] * vf[c][0] + u[c][1] * vf[c][1]
                + u[c][2] * vf[c][2] + u[c][3] * vf[c][3];
        a += __shfl_xor(a, 1);
        a += __shfl_xor(a, 2);
        bij[c] = a;
      }
      // softmax over c (10 values, in-register)
      float m = bij[0];
      #pragma unroll
      for (int c = 1; c < C_N; ++c) m = fmaxf(m, bij[c]);
      float e[C_N];
      float den = 0.0f;
      #pragma unroll
      for (int c = 0; c < C_N; ++c) { e[c] = __expf(bij[c] - m); den += e[c]; }
      const float inv = __builtin_amdgcn_rcpf(den);
      #pragma unroll
      for (int c = 0; c < C_N; ++c) {
        const float cc = e[c] * inv;
        #pragma unroll
        for (int j = 0; j < 4; ++j) sacc[c][j] += cc * u[c][j];
      }
    }
  }

  // plain coalesced partial store: part[rtile][b][c][obase..obase+3]
  const float scale = UNIFORM ? 0.1f : 1.0f;
  float* p = part + (size_t)rtile * SEG + ((size_t)b * C_N) * O_N + obase;
  #pragma unroll
  for (int c = 0; c < C_N; ++c) {
    float4 v;
    v.x = sacc[c][0] * scale; v.y = sacc[c][1] * scale;
    v.z = sacc[c][2] * scale; v.w = sacc[c][3] * scale;
    *reinterpret_cast<float4*>(p + c * O_N) = v;
  }
}

// fused reduce-over-rtiles + squash over O=16 per (b,c); 16 consecutive lanes per group.
// MODE 0: vsum = v ; MODE 1: vsum += v ; MODE 2: out = v
template<int MODE>
__global__ __launch_bounds__(256) void reduce_squash(
    const float* __restrict__ part, int nrt,
    float* __restrict__ vsum, float* __restrict__ out)
{
  const int gt = blockIdx.x * 256 + threadIdx.x;   // 0 .. 81919
  const int o  = gt & 15;
  const int g  = gt >> 4;                          // b*10 + c
  const float* p = part + (g << 4) + o;
  float sv = 0.0f;
  #pragma unroll 4
  for (int rt = 0; rt < nrt; ++rt) sv += p[(size_t)rt * SEG];

  float sq = sv * sv;
  sq += __shfl_xor(sq, 1);
  sq += __shfl_xor(sq, 2);
  sq += __shfl_xor(sq, 4);
  sq += __shfl_xor(sq, 8);
  const float scale = sq / (1.0f + sq) * rsqrtf(sq + 1e-8f);
  const float v = scale * sv;
  if constexpr (MODE == 0)      vsum[(g << 4) + o] = v;
  else if constexpr (MODE == 1) vsum[(g << 4) + o] += v;
  else                          out[(g << 4) + o] = v;
}

extern "C" void kernel_launch(void* const* d_in, const int* in_sizes, int n_in,
                              void* d_out, int out_size, void* d_ws, size_t ws_size,
                              hipStream_t stream) {
  (void)in_sizes; (void)n_in; (void)out_size;
  const float* x = (const float*)d_in[0];
  const float* W = (const float*)d_in[1];
  float* out  = (float*)d_out;        // doubles as vsum scratch; fully rewritten with v2
  float* part = (float*)d_ws;

  // adaptive r-tiling: largest power-of-two RT whose partials fit in d_ws
  int RT = 64;
  while (RT > 1 && (size_t)RT * SEG * sizeof(float) > ws_size) RT >>= 1;
  const int RCH = R_TOT / RT;

  const dim3 accGrid(RT, 8), blk(256), sqGrid(SEG / 256);

  // iter 0: uniform coefficients (softmax of zeros)
  hipLaunchKernelGGL((acc_kernel<true>),  accGrid, blk, 0, stream, x, W, nullptr, part, RCH);
  hipLaunchKernelGGL((reduce_squash<0>),  sqGrid,  blk, 0, stream, part, RT, out, out);  // vsum = v0

  // iter 1
  hipLaunchKernelGGL((acc_kernel<false>), accGrid, blk, 0, stream, x, W, out, part, RCH);
  hipLaunchKernelGGL((reduce_squash<1>),  sqGrid,  blk, 0, stream, part, RT, out, out);  // vsum = v0+v1

  // iter 2
  hipLaunchKernelGGL((acc_kernel<false>), accGrid, blk, 0, stream, x, W, out, part, RCH);
  hipLaunchKernelGGL((reduce_squash<2>),  sqGrid,  blk, 0, stream, part, RT, out, out);  // out = v2
}